// Round 1
// baseline (14974.504 us; speedup 1.0000x reference)
//
#include <hip/hip_runtime.h>
#include <math.h>

// SE3Net forward, fp32. Structure:
//   lowpass(x) -> conv1(5^3) -> gated -> [conv2*lowpass fused as 9^3 s2] -> gated
//   -> [conv3*lowpass fused 9^3 s2] -> gated -> conv4(5^3) -> relu+avg -> linear
// Fusion identity: conv(pad4,s1) then gauss5(pad2,s2)  ==  conv9(pad6,s2) with E = W (*) G.

struct GaussW { float g[5]; };

#define B_ 16

// ---------------- input low-pass (depthwise 5^3 gaussian, 32^3, pad 2) ----------------
__global__ __launch_bounds__(256) void k_lowpass_in(
    const float* __restrict__ x, float* __restrict__ out, GaussW gw)
{
  int idx = blockIdx.x * 256 + threadIdx.x;
  const int total = B_ * 32 * 32 * 32;
  if (idx >= total) return;
  int b = idx >> 15;
  int r = idx & 32767;
  int z = r >> 10, y = (r >> 5) & 31, xx = r & 31;
  const float* xb = x + ((size_t)b << 15);
  float s = 0.f;
  #pragma unroll
  for (int dz = 0; dz < 5; ++dz) {
    int zi = z + dz - 2;
    if (zi < 0 || zi >= 32) continue;
    float gz = gw.g[dz];
    #pragma unroll
    for (int dy = 0; dy < 5; ++dy) {
      int yi = y + dy - 2;
      if (yi < 0 || yi >= 32) continue;
      float gzy = gz * gw.g[dy];
      #pragma unroll
      for (int dx = 0; dx < 5; ++dx) {
        int xi = xx + dx - 2;
        if (xi < 0 || xi >= 32) continue;
        s = fmaf(gzy * gw.g[dx], xb[(zi << 10) + (yi << 5) + xi], s);
      }
    }
  }
  out[idx] = s;
}

// ---------------- weight transpose: W[co][ci][5^3] -> Wt[ci][k][co] ----------------
template<int CIN, int COUT>
__global__ __launch_bounds__(256) void k_transpose_w(
    const float* __restrict__ W, float* __restrict__ Wt)
{
  int idx = blockIdx.x * 256 + threadIdx.x;
  constexpr int TOT = CIN * 125 * COUT;
  if (idx >= TOT) return;
  int co = idx % COUT;
  int k  = (idx / COUT) % 125;
  int ci = idx / (COUT * 125);
  Wt[idx] = W[((size_t)co * CIN + ci) * 125 + k];
}

// ---------------- expand W (*) gauss -> 9^3 kernel, layout Et[ci][t][co] ----------------
template<int CIN, int COUT>
__global__ __launch_bounds__(256) void k_expand(
    const float* __restrict__ W, float* __restrict__ Et, GaussW gw)
{
  int idx = blockIdx.x * 256 + threadIdx.x;
  constexpr int TOT = CIN * 729 * COUT;
  if (idx >= TOT) return;
  int co = idx % COUT;
  int t  = (idx / COUT) % 729;
  int ci = idx / (COUT * 729);
  int tz = t / 81, ty = (t / 9) % 9, tx = t % 9;
  const float* Wp = W + ((size_t)co * CIN + ci) * 125;
  int kz0 = tz - 4 > 0 ? tz - 4 : 0, kz1 = tz < 4 ? tz : 4;
  int ky0 = ty - 4 > 0 ? ty - 4 : 0, ky1 = ty < 4 ? ty : 4;
  int kx0 = tx - 4 > 0 ? tx - 4 : 0, kx1 = tx < 4 ? tx : 4;
  float s = 0.f;
  for (int kz = kz0; kz <= kz1; ++kz) {
    float gz = gw.g[tz - kz];
    for (int ky = ky0; ky <= ky1; ++ky) {
      float gzy = gz * gw.g[ty - ky];
      for (int kx = kx0; kx <= kx1; ++kx)
        s = fmaf(gzy * gw.g[tx - kx], Wp[kz * 25 + ky * 5 + kx], s);
    }
  }
  Et[idx] = s;
}

// ---------------- tiled direct conv ----------------
// in:  [B][CIN][DIN^3]   wt: [CIN][KS][KS*KS][COUT]   out: [B][COUT][DOUT^3]
// Block: co-tile COB x spatial tile (ZT planes over flattened (b,z)) x (YT rows) x full X.
// Per (ci,kz): stage ZT padded input planes + 81*COB weights in LDS, then
// each thread: NSP positions x COB channel accumulators.
template<int KS, int S, int CIN, int CSPLIT, int COUT, int COB, int DIN, int DOUT,
         int PAD, int ZT, int YT, int NSP, bool ATOMIC>
__global__ __launch_bounds__(256)
void conv_tiled(const float* __restrict__ in, const float* __restrict__ wt,
                float* __restrict__ out)
{
  constexpr int XIN = (DOUT - 1) * S + KS;
  constexpr int YIN = (YT - 1) * S + KS;
  constexpr int PL  = YIN * XIN;
  constexpr int NYT = (DOUT + YT - 1) / YT;
  constexpr int TILE = ZT * YT * DOUT;
  constexpr int NIN = ZT * PL;
  static_assert(TILE <= 256 * NSP, "tile too big");
  static_assert(CIN % CSPLIT == 0, "bad split");
  __shared__ __align__(16) float s_in[NIN];
  __shared__ __align__(16) float s_w[KS * KS * COB];

  const int tid = threadIdx.x;
  const int sp  = blockIdx.x;        // bzt*NYT + yt
  const int bzt = sp / NYT;
  const int yt  = sp - bzt * NYT;
  const int cb  = blockIdx.y;
  const int ksp = blockIdx.z;        // ci split
  const int bz0 = bzt * ZT;
  const int y0  = yt * YT;
  constexpr int BZ = B_ * DOUT;

  int   lbase[NSP];
  bool  act[NSP];
  int   bj[NSP], ozj[NSP], oyj[NSP], oxj[NSP];
  #pragma unroll
  for (int j = 0; j < NSP; ++j) {
    int idx = tid + j * 256;
    bool a = idx < TILE;
    int idc = a ? idx : 0;
    int tz = idc / (YT * DOUT);
    int r  = idc - tz * (YT * DOUT);
    int ty = r / DOUT;
    int tx = r - ty * DOUT;
    int bz = bz0 + tz;
    a = a && (bz < BZ) && (y0 + ty < DOUT);
    act[j] = a;
    lbase[j] = tz * PL + (ty * S) * XIN + tx * S;
    bj[j] = bz / DOUT;
    ozj[j] = bz - bj[j] * DOUT;
    oyj[j] = y0 + ty;
    oxj[j] = tx;
  }
  float acc[NSP][COB];
  #pragma unroll
  for (int j = 0; j < NSP; ++j)
    #pragma unroll
    for (int c = 0; c < COB; ++c) acc[j][c] = 0.f;

  constexpr int CI_PER = CIN / CSPLIT;
  const int ci0 = ksp * CI_PER;

  for (int cii = 0; cii < CI_PER; ++cii) {
    const int ci = ci0 + cii;
    for (int kz = 0; kz < KS; ++kz) {
      __syncthreads();
      // ---- stage input planes (zero-padded) ----
      for (int i = tid; i < NIN; i += 256) {
        int tz = i / PL;
        int r  = i - tz * PL;
        int yy = r / XIN;
        int xx = r - yy * XIN;
        int bz = bz0 + tz;
        int b_ = bz / DOUT;
        int oz = bz - b_ * DOUT;
        int zin = oz * S + kz - PAD;
        int yin = y0 * S + yy - PAD;
        int xin = xx - PAD;
        float v = 0.f;
        if (bz < BZ && zin >= 0 && zin < DIN && yin >= 0 && yin < DIN &&
            xin >= 0 && xin < DIN)
          v = in[(((size_t)b_ * CIN + ci) * DIN + zin) * (DIN * DIN) +
                 yin * DIN + xin];
        s_in[i] = v;
      }
      // ---- stage weights [k][COB] ----
      const float* wsrc = wt + ((size_t)(ci * KS + kz) * (KS * KS)) * COUT + cb * COB;
      for (int i = tid; i < KS * KS * COB; i += 256) {
        int k = i / COB;
        int c = i - k * COB;
        float wv = 0.f;
        if (cb * COB + c < COUT) wv = wsrc[(size_t)k * COUT + c];
        s_w[i] = wv;
      }
      __syncthreads();
      // ---- accumulate ----
      #pragma unroll 1
      for (int ky = 0; ky < KS; ++ky) {
        for (int kx = 0; kx < KS; ++kx) {
          const float* wp = &s_w[(ky * KS + kx) * COB];
          float wv[COB];
          #pragma unroll
          for (int c = 0; c < COB; c += 4) {
            float4 t4 = *reinterpret_cast<const float4*>(wp + c);
            wv[c] = t4.x; wv[c + 1] = t4.y; wv[c + 2] = t4.z; wv[c + 3] = t4.w;
          }
          #pragma unroll
          for (int j = 0; j < NSP; ++j) {
            float iv = s_in[lbase[j] + ky * XIN + kx];
            #pragma unroll
            for (int c = 0; c < COB; ++c)
              acc[j][c] = fmaf(iv, wv[c], acc[j][c]);
          }
        }
      }
    }
  }
  // ---- store ----
  #pragma unroll
  for (int j = 0; j < NSP; ++j) {
    if (!act[j]) continue;
    size_t ob = (((size_t)bj[j] * COUT + (size_t)cb * COB) * DOUT + ozj[j]) *
                    (size_t)(DOUT * DOUT) +
                oyj[j] * DOUT + oxj[j];
    #pragma unroll
    for (int c = 0; c < COB; ++c) {
      if (cb * COB + c < COUT) {
        size_t o = ob + (size_t)c * DOUT * DOUT * DOUT;
        if constexpr (ATOMIC) atomicAdd(&out[o], acc[j][c]);
        else out[o] = acc[j][c];
      }
    }
  }
}

// ---------------- gated nonlinearity ----------------
__global__ __launch_bounds__(256) void k_gated(
    const float* __restrict__ in, float* __restrict__ out,
    int S3, int Cin, int n_scalar, int n_gate,
    int m1, int d1, int m2, int d2, int m3, int d3, int n_out)
{
  int idx = blockIdx.x * 256 + threadIdx.x;
  int oc = blockIdx.y;
  int b  = blockIdx.z;
  if (idx >= S3) return;
  const float* inb = in + (size_t)b * Cin * S3;
  float val;
  if (oc < n_scalar) {
    float v = inb[(size_t)oc * S3 + idx];
    val = v > 0.f ? v : 0.f;
  } else {
    int o = oc - n_scalar;
    int gate_ch;
    if (o < m1 * d1) gate_ch = n_scalar + o / d1;
    else if (o - m1 * d1 < m2 * d2) gate_ch = n_scalar + m1 + (o - m1 * d1) / d2;
    else gate_ch = n_scalar + m1 + m2 + (o - m1 * d1 - m2 * d2) / d3;
    int feat_ch = n_scalar + n_gate + o;
    float v = inb[(size_t)feat_ch * S3 + idx];
    float g = inb[(size_t)gate_ch * S3 + idx];
    val = v / (1.f + expf(-g));      // v * sigmoid(g)
  }
  out[((size_t)b * n_out + oc) * S3 + idx] = val;
}

// ---------------- relu + spatial mean (conv4 out is pre-relu) ----------------
__global__ __launch_bounds__(256) void k_relu_avg(
    const float* __restrict__ in, float* __restrict__ h)
{
  int bc = blockIdx.x;               // b*64 + c
  const float* p = in + (size_t)bc * 4096;
  float s = 0.f;
  for (int i = threadIdx.x; i < 4096; i += 256) {
    float v = p[i];
    s += fmaxf(v, 0.f);
  }
  #pragma unroll
  for (int off = 32; off > 0; off >>= 1) s += __shfl_down(s, off, 64);
  __shared__ float wsum[4];
  int wid = threadIdx.x >> 6;
  if ((threadIdx.x & 63) == 0) wsum[wid] = s;
  __syncthreads();
  if (threadIdx.x == 0)
    h[bc] = (wsum[0] + wsum[1] + wsum[2] + wsum[3]) * (1.f / 4096.f);
}

// ---------------- final linear [16,64] @ [10,64]^T + b ----------------
__global__ __launch_bounds__(256) void k_linear(
    const float* __restrict__ h, const float* __restrict__ Wl,
    const float* __restrict__ bl, float* __restrict__ out)
{
  int t = threadIdx.x;
  if (t >= 160) return;
  int b = t / 10, o = t - b * 10;
  const float* hp = h + b * 64;
  const float* wp = Wl + o * 64;
  float s = bl[o];
  #pragma unroll
  for (int c = 0; c < 64; ++c) s = fmaf(hp[c], wp[c], s);
  out[t] = s;
}

extern "C" void kernel_launch(void* const* d_in, const int* in_sizes, int n_in,
                              void* d_out, int out_size, void* d_ws, size_t ws_size,
                              hipStream_t stream)
{
  const float* x  = (const float*)d_in[0];
  const float* W1 = (const float*)d_in[1];
  const float* W2 = (const float*)d_in[2];
  const float* W3 = (const float*)d_in[3];
  const float* W4 = (const float*)d_in[4];
  const float* Wl = (const float*)d_in[5];
  const float* bl = (const float*)d_in[6];
  float* out = (float*)d_out;
  float* ws  = (float*)d_ws;

  // gaussian taps (scale=2): sigma=0.5*sqrt(3), size 5, normalized per dim
  GaussW gw;
  {
    double gv[5], sum = 0.0;
    for (int i = 0; i < 5; ++i) { double r = i - 2; gv[i] = exp(-r * r / 1.5); sum += gv[i]; }
    for (int i = 0; i < 5; ++i) gw.g[i] = (float)(gv[i] / sum);
  }

  // workspace layout (floats), 64-float aligned
  size_t off = 0;
  auto A = [&](size_t n) { size_t o = off; off += (n + 63) & ~(size_t)63; return o; };
  size_t o_lp  = A(524288);                 // lowpassed input 16x1x32^3
  size_t o_W1t = A(30 * 125);
  size_t o_E2t = A((size_t)25 * 729 * 88);  // fused conv2 9^3 kernel
  size_t o_E3t = A((size_t)72 * 729 * 96);
  size_t o_W4t = A((size_t)80 * 125 * 64);
  size_t o_h   = A(1024);
  size_t o_R2  = A(22394880);               // c1 / c2 / c3 / c4
  size_t o_R3  = A(18662400);               // g1 / g2 / g3
  if (ws_size < off * sizeof(float)) return;

  float* lp  = ws + o_lp;
  float* W1t = ws + o_W1t;
  float* E2t = ws + o_E2t;
  float* E3t = ws + o_E3t;
  float* W4t = ws + o_W4t;
  float* hb  = ws + o_h;
  float* R2  = ws + o_R2;
  float* R3  = ws + o_R3;

  // 0. weight prep + input low-pass
  k_lowpass_in<<<(524288 + 255) / 256, 256, 0, stream>>>(x, lp, gw);
  k_transpose_w<1, 30><<<(3750 + 255) / 256, 256, 0, stream>>>(W1, W1t);
  k_expand<25, 88><<<((25 * 729 * 88) + 255) / 256, 256, 0, stream>>>(W2, E2t, gw);
  k_expand<72, 96><<<((72 * 729 * 96) + 255) / 256, 256, 0, stream>>>(W3, E3t, gw);
  k_transpose_w<80, 64><<<(640000 + 255) / 256, 256, 0, stream>>>(W4, W4t);

  // 1. conv1: lp(1,32^3) -> R2(30,36^3)
  {
    dim3 g(192 * 4, 2, 1);  // 192 bz-tiles(ZT=3) x 4 y-tiles, 2 co-tiles
    conv_tiled<5, 1, 1, 1, 30, 16, 32, 36, 4, 3, 9, 4, false>
        <<<g, 256, 0, stream>>>(lp, W1t, R2);
  }
  // gated1 -> R3(25,36^3)
  {
    dim3 g((46656 + 255) / 256, 25, 16);
    k_gated<<<g, 256, 0, stream>>>(R2, R3, 46656, 30, 2, 5, 2, 3, 2, 5, 1, 7, 25);
  }
  // 2. fused conv2+lowpass: R3(25,36^3) -> R2(88,20^3)
  {
    dim3 g(160, 6, 1);      // 160 bz-tiles(ZT=2), 6 co-tiles
    conv_tiled<9, 2, 25, 1, 88, 16, 36, 20, 6, 2, 20, 4, false>
        <<<g, 256, 0, stream>>>(R3, E2t, R2);
  }
  // gated2 -> R3(72,20^3)
  {
    dim3 g((8000 + 255) / 256, 72, 16);
    k_gated<<<g, 256, 0, stream>>>(R2, R3, 8000, 88, 8, 16, 8, 3, 8, 5, 0, 1, 72);
  }
  // 3. fused conv3+lowpass: R3(72,20^3) -> R2(96,12^3), ci split 4, atomic
  hipMemsetAsync(R2, 0, (size_t)2654208 * 4, stream);
  {
    dim3 g(28, 6, 4);       // 28 bz-tiles(ZT=7), 6 co-tiles, 4 ci-splits
    conv_tiled<9, 2, 72, 4, 96, 16, 20, 12, 6, 7, 12, 4, true>
        <<<g, 256, 0, stream>>>(R3, E3t, R2);
  }
  // gated3 -> R3(80,12^3)
  {
    dim3 g((1728 + 255) / 256, 80, 16);
    k_gated<<<g, 256, 0, stream>>>(R2, R3, 1728, 96, 16, 16, 8, 3, 8, 5, 0, 1, 80);
  }
  // 4. conv4: R3(80,12^3) -> R2(64,16^3), ci split 4, atomic
  hipMemsetAsync(R2, 0, (size_t)4194304 * 4, stream);
  {
    dim3 g(64, 4, 4);       // 64 bz-tiles(ZT=4), 4 co-tiles, 4 ci-splits
    conv_tiled<5, 1, 80, 4, 64, 16, 12, 16, 4, 4, 16, 4, true>
        <<<g, 256, 0, stream>>>(R3, W4t, R2);
  }
  // 5. relu + spatial mean -> hb[16*64]
  k_relu_avg<<<1024, 256, 0, stream>>>(R2, hb);
  // 6. linear -> out[16*10]
  k_linear<<<1, 256, 0, stream>>>(hb, Wl, bl, out);
}

// Round 2
// 6797.693 us; speedup vs baseline: 2.2029x; 2.2029x over previous
//
#include <hip/hip_runtime.h>
#include <math.h>

// SE3Net forward, fp32, restructured:
//   blur(x) -> conv1(5^3,p4) -> gated -> blurE -> conv2(5^3,s2,p2) -> gated
//   -> blurE -> conv3(5^3,s2,p2) -> gated -> conv4(5^3,p4) -> relu+avg -> linear
// Identity used: conv(pad4,s1) is a FULL convolution, so
//   downsample_s(G * (W * x)) == downsample_s(W * (G_expanded * x))
// where G_expanded is the Gaussian blur stored on its full support (D -> D+4).
// This turns the fused 9^3 convs into 5^3 convs (779 -> 208 GFLOP) and removes
// all atomics / ci-splits.

struct GaussW { float g[5]; };
#define B_ 16

// ---------------- 3D gaussian blur; EXPAND=0: same-size (pad2 crop, = reference
// low_pass stride1); EXPAND=1: full support, D -> D+4 ----------------
template<int C, int DIN, int EXPAND>
__global__ __launch_bounds__(256) void blur3d(
    const float* __restrict__ in, float* __restrict__ out, GaussW gw)
{
  constexpr int DOUT = DIN + (EXPAND ? 4 : 0);
  constexpr int OFF  = EXPAND ? 4 : 2;
  constexpr int TOT  = B_ * C * DOUT * DOUT * DOUT;
  int idx = blockIdx.x * 256 + threadIdx.x;
  if (idx >= TOT) return;
  int x = idx % DOUT;
  int t = idx / DOUT;
  int y = t % DOUT;
  t /= DOUT;
  int z = t % DOUT;
  int bc = t / DOUT;
  const float* p = in + (size_t)bc * (DIN * DIN * DIN);
  float sz_ = 0.f;
  #pragma unroll
  for (int tz = 0; tz < 5; ++tz) {
    int gz = z + tz - OFF;
    if (gz < 0 || gz >= DIN) continue;
    float sy_ = 0.f;
    #pragma unroll
    for (int ty = 0; ty < 5; ++ty) {
      int gy = y + ty - OFF;
      if (gy < 0 || gy >= DIN) continue;
      const float* row = p + (gz * DIN + gy) * DIN;
      float sx_ = 0.f;
      #pragma unroll
      for (int tx = 0; tx < 5; ++tx) {
        int gx = x + tx - OFF;
        if (gx >= 0 && gx < DIN) sx_ = fmaf(gw.g[tx], row[gx], sx_);
      }
      sy_ = fmaf(gw.g[ty], sx_, sy_);
    }
    sz_ = fmaf(gw.g[tz], sy_, sz_);
  }
  out[idx] = sz_;
}

// ---------------- weight transpose: W[co][ci][125] -> Wt[ci][k][co] ----------------
template<int CIN, int COUT>
__global__ __launch_bounds__(256) void k_transpose_w(
    const float* __restrict__ W, float* __restrict__ Wt)
{
  int idx = blockIdx.x * 256 + threadIdx.x;
  constexpr int TOT = CIN * 125 * COUT;
  if (idx >= TOT) return;
  int co = idx % COUT;
  int k  = (idx / COUT) % 125;
  int ci = idx / (COUT * 125);
  Wt[idx] = W[((size_t)co * CIN + ci) * 125 + k];
}

// ---------------- tiled direct 5^3 conv ----------------
// in: [B][CIN][DIN^3]  wt: [CIN][125][COUT]  out: [B][COUT][DOUT^3]
// Block: COB out-channels x (ZT z-planes x YT rows x full X). Per ci: stage the
// whole (ZIN,YIN,XIN) input tile + 125*COB weights once, then 5^3 accumulate.
// For S==2 the LDS x-axis is parity-de-interleaved so stride-2 reads are
// conflict-free. ZT must divide DOUT (tiles never straddle batch boundary).
template<int S, int CIN, int COUT, int COB, int DIN, int DOUT, int PAD,
         int ZT, int YT, int NSP>
__global__ __launch_bounds__(256)
void conv5(const float* __restrict__ in, const float* __restrict__ wt,
           float* __restrict__ out)
{
  static_assert(COB == 8, "store path hardcodes COB==8 float4 pairs");
  constexpr int K   = 5;
  constexpr int XIN = (DOUT - 1) * S + K;
  constexpr int YIN = (YT - 1) * S + K;
  constexpr int ZIN = (ZT - 1) * S + K;
  constexpr int HX  = (S == 2) ? (XIN + 1) / 2 : 0;
  constexpr int XW  = (S == 2) ? 2 * HX : XIN;
  constexpr int PL  = YIN * XW;
  constexpr int NIN = ZIN * PL;
  static_assert(DOUT % ZT == 0, "ZT must divide DOUT");
  constexpr int NZT = DOUT / ZT;
  constexpr int NYT = (DOUT + YT - 1) / YT;
  constexpr int TILE = ZT * YT * DOUT;
  static_assert(TILE <= 256 * NSP, "NSP too small");
  constexpr int D2  = DOUT * DOUT;
  constexpr int DI2 = DIN * DIN;

  __shared__ __align__(16) float s_in[NIN];
  __shared__ __align__(16) float s_w[125 * COB];

  const int tid = threadIdx.x;
  const int bx  = blockIdx.x;
  const int yt  = bx % NYT;
  const int bzt = bx / NYT;
  const int b   = bzt / NZT;
  const int zt  = bzt - b * NZT;
  const int cb  = blockIdx.y;
  const int oz0 = zt * ZT;
  const int y0  = yt * YT;
  const int co0 = cb * COB;

  int lbase[NSP];
  #pragma unroll
  for (int j = 0; j < NSP; ++j) {
    int idx = tid + j * 256;
    int idc = idx < TILE ? idx : 0;
    int tz = idc / (YT * DOUT);
    int r  = idc - tz * (YT * DOUT);
    int ty = r / DOUT;
    int tx = r - ty * DOUT;
    lbase[j] = (tz * S) * PL + (ty * S) * XW + tx;
  }

  float acc[NSP][COB];
  #pragma unroll
  for (int j = 0; j < NSP; ++j)
    #pragma unroll
    for (int c = 0; c < COB; ++c) acc[j][c] = 0.f;

  #pragma unroll 1
  for (int ci = 0; ci < CIN; ++ci) {
    __syncthreads();
    // ---- stage input tile (zero-padded, parity-de-interleaved if S==2) ----
    const float* gsrc = in + ((size_t)b * CIN + ci) * (DIN * DI2);
    for (int i = tid; i < NIN; i += 256) {
      int sz = i / PL;
      int r  = i - sz * PL;
      int sy = r / XW;
      int sx = r - sy * XW;
      int u  = (S == 2) ? ((sx < HX) ? (sx << 1) : (((sx - HX) << 1) | 1)) : sx;
      int gz = oz0 * S + sz - PAD;
      int gy = y0 * S + sy - PAD;
      int gx = u - PAD;
      float v = 0.f;
      if (gz >= 0 && gz < DIN && gy >= 0 && gy < DIN && gx >= 0 && gx < DIN)
        v = gsrc[gz * DI2 + gy * DIN + gx];
      s_in[i] = v;
    }
    // ---- stage weights [125][COB] ----
    const float* wsrc = wt + (size_t)ci * 125 * COUT + co0;
    for (int i = tid; i < 125 * COB; i += 256) {
      int k = i / COB;
      int c = i - k * COB;
      s_w[i] = (co0 + c < COUT) ? wsrc[k * COUT + c] : 0.f;
    }
    __syncthreads();
    // ---- accumulate ----
    #pragma unroll 1
    for (int kz = 0; kz < K; ++kz) {
      #pragma unroll 1
      for (int ky = 0; ky < K; ++ky) {
        const int rb = kz * PL + ky * XW;
        const float* wr = s_w + (kz * 25 + ky * 5) * COB;
        int ib[NSP];
        #pragma unroll
        for (int j = 0; j < NSP; ++j) ib[j] = lbase[j] + rb;
        #pragma unroll
        for (int kx = 0; kx < K; ++kx) {
          const int kxo = (S == 2) ? ((kx & 1) * HX + (kx >> 1)) : kx;
          float4 wa = *reinterpret_cast<const float4*>(wr + kx * COB);
          float4 wb = *reinterpret_cast<const float4*>(wr + kx * COB + 4);
          float iv[NSP];
          #pragma unroll
          for (int j = 0; j < NSP; ++j) iv[j] = s_in[ib[j] + kxo];
          #pragma unroll
          for (int j = 0; j < NSP; ++j) {
            acc[j][0] = fmaf(iv[j], wa.x, acc[j][0]);
            acc[j][1] = fmaf(iv[j], wa.y, acc[j][1]);
            acc[j][2] = fmaf(iv[j], wa.z, acc[j][2]);
            acc[j][3] = fmaf(iv[j], wa.w, acc[j][3]);
            acc[j][4] = fmaf(iv[j], wb.x, acc[j][4]);
            acc[j][5] = fmaf(iv[j], wb.y, acc[j][5]);
            acc[j][6] = fmaf(iv[j], wb.z, acc[j][6]);
            acc[j][7] = fmaf(iv[j], wb.w, acc[j][7]);
          }
        }
      }
    }
  }
  // ---- store ----
  #pragma unroll
  for (int j = 0; j < NSP; ++j) {
    int idx = tid + j * 256;
    if (idx >= TILE) continue;
    int tz = idx / (YT * DOUT);
    int r  = idx - tz * (YT * DOUT);
    int ty = r / DOUT;
    int tx = r - ty * DOUT;
    int oy = y0 + ty;
    if (oy >= DOUT) continue;
    size_t obase = (((size_t)b * COUT + co0) * DOUT + (oz0 + tz)) * D2 +
                   oy * DOUT + tx;
    #pragma unroll
    for (int c = 0; c < COB; ++c)
      if (co0 + c < COUT) out[obase + (size_t)c * DOUT * D2] = acc[j][c];
  }
}

// ---------------- gated nonlinearity ----------------
__global__ __launch_bounds__(256) void k_gated(
    const float* __restrict__ in, float* __restrict__ out,
    int S3, int Cin, int n_scalar, int n_gate,
    int m1, int d1, int m2, int d2, int m3, int d3, int n_out)
{
  int idx = blockIdx.x * 256 + threadIdx.x;
  int oc = blockIdx.y;
  int b  = blockIdx.z;
  if (idx >= S3) return;
  const float* inb = in + (size_t)b * Cin * S3;
  float val;
  if (oc < n_scalar) {
    float v = inb[(size_t)oc * S3 + idx];
    val = v > 0.f ? v : 0.f;
  } else {
    int o = oc - n_scalar;
    int gate_ch;
    if (o < m1 * d1) gate_ch = n_scalar + o / d1;
    else if (o - m1 * d1 < m2 * d2) gate_ch = n_scalar + m1 + (o - m1 * d1) / d2;
    else gate_ch = n_scalar + m1 + m2 + (o - m1 * d1 - m2 * d2) / d3;
    int feat_ch = n_scalar + n_gate + o;
    float v = inb[(size_t)feat_ch * S3 + idx];
    float g = inb[(size_t)gate_ch * S3 + idx];
    val = v / (1.f + expf(-g));      // v * sigmoid(g)
  }
  out[((size_t)b * n_out + oc) * S3 + idx] = val;
}

// ---------------- relu + spatial mean ----------------
__global__ __launch_bounds__(256) void k_relu_avg(
    const float* __restrict__ in, float* __restrict__ h)
{
  int bc = blockIdx.x;               // b*64 + c
  const float* p = in + (size_t)bc * 4096;
  float s = 0.f;
  for (int i = threadIdx.x; i < 4096; i += 256) {
    float v = p[i];
    s += fmaxf(v, 0.f);
  }
  #pragma unroll
  for (int off = 32; off > 0; off >>= 1) s += __shfl_down(s, off, 64);
  __shared__ float wsum[4];
  int wid = threadIdx.x >> 6;
  if ((threadIdx.x & 63) == 0) wsum[wid] = s;
  __syncthreads();
  if (threadIdx.x == 0)
    h[bc] = (wsum[0] + wsum[1] + wsum[2] + wsum[3]) * (1.f / 4096.f);
}

// ---------------- final linear [16,64] @ [10,64]^T + b ----------------
__global__ __launch_bounds__(256) void k_linear(
    const float* __restrict__ h, const float* __restrict__ Wl,
    const float* __restrict__ bl, float* __restrict__ out)
{
  int t = threadIdx.x;
  if (t >= 160) return;
  int b = t / 10, o = t - b * 10;
  const float* hp = h + b * 64;
  const float* wp = Wl + o * 64;
  float s = bl[o];
  #pragma unroll
  for (int c = 0; c < 64; ++c) s = fmaf(hp[c], wp[c], s);
  out[t] = s;
}

extern "C" void kernel_launch(void* const* d_in, const int* in_sizes, int n_in,
                              void* d_out, int out_size, void* d_ws, size_t ws_size,
                              hipStream_t stream)
{
  const float* x  = (const float*)d_in[0];
  const float* W1 = (const float*)d_in[1];
  const float* W2 = (const float*)d_in[2];
  const float* W3 = (const float*)d_in[3];
  const float* W4 = (const float*)d_in[4];
  const float* Wl = (const float*)d_in[5];
  const float* bl = (const float*)d_in[6];
  float* out = (float*)d_out;
  float* ws  = (float*)d_ws;

  // gaussian taps (scale=2): sigma=0.5*sqrt(3), size 5, normalized
  GaussW gw;
  {
    double gv[5], sum = 0.0;
    for (int i = 0; i < 5; ++i) { double r = i - 2; gv[i] = exp(-r * r / 1.5); sum += gv[i]; }
    for (int i = 0; i < 5; ++i) gw.g[i] = (float)(gv[i] / sum);
  }

  // workspace (floats), 64-aligned chunks
  size_t off = 0;
  auto A = [&](size_t n) { size_t o = off; off += (n + 63) & ~(size_t)63; return o; };
  size_t o_lp  = A(524288);            // blurred input 16x1x32^3
  size_t o_W1t = A(3750);
  size_t o_W2t = A(275000);
  size_t o_W3t = A(864000);
  size_t o_W4t = A(640000);
  size_t o_h   = A(1024);
  size_t o_B1  = A(25600000);          // max: blur2 out 16x25x40^3
  size_t o_B2  = A(18662400);          // max: gated1 out 16x25x36^3
  if (ws_size < off * sizeof(float)) return;

  float* lp  = ws + o_lp;
  float* W1t = ws + o_W1t;
  float* W2t = ws + o_W2t;
  float* W3t = ws + o_W3t;
  float* W4t = ws + o_W4t;
  float* hb  = ws + o_h;
  float* B1  = ws + o_B1;
  float* B2  = ws + o_B2;

  // weight prep + input low-pass (cropped, = reference low_pass(x,1))
  blur3d<1, 32, 0><<<(524288 + 255) / 256, 256, 0, stream>>>(x, lp, gw);
  k_transpose_w<1, 30><<<15, 256, 0, stream>>>(W1, W1t);
  k_transpose_w<25, 88><<<(275000 + 255) / 256, 256, 0, stream>>>(W2, W2t);
  k_transpose_w<72, 96><<<(864000 + 255) / 256, 256, 0, stream>>>(W3, W3t);
  k_transpose_w<80, 64><<<(640000 + 255) / 256, 256, 0, stream>>>(W4, W4t);

  // conv1: lp(1,32^3) -> B1(30,36^3)   [S1 pad4]
  conv5<1, 1, 30, 8, 32, 36, 4, 2, 14, 4>
      <<<dim3(16 * 18 * 3, 4), 256, 0, stream>>>(lp, W1t, B1);
  // gated1 -> B2(25,36^3)
  k_gated<<<dim3(183, 25, 16), 256, 0, stream>>>(B1, B2, 46656, 30, 2, 5, 2, 3, 2, 5, 1, 7, 25);
  // expanded blur: B2(25,36^3) -> B1(25,40^3)
  blur3d<25, 36, 1><<<(25600000 + 255) / 256, 256, 0, stream>>>(B2, B1, gw);
  // conv2: B1(25,40^3) -> B2(88,20^3)  [S2 pad2]
  conv5<2, 25, 88, 8, 40, 20, 2, 5, 10, 4>
      <<<dim3(128, 11), 256, 0, stream>>>(B1, W2t, B2);
  // gated2 -> B1(72,20^3)
  k_gated<<<dim3(32, 72, 16), 256, 0, stream>>>(B2, B1, 8000, 88, 8, 16, 8, 3, 8, 5, 0, 1, 72);
  // expanded blur: B1(72,20^3) -> B2(72,24^3)
  blur3d<72, 20, 1><<<(15925248 + 255) / 256, 256, 0, stream>>>(B1, B2, gw);
  // conv3: B2(72,24^3) -> B1(96,12^3)  [S2 pad2]
  conv5<2, 72, 96, 8, 24, 12, 2, 4, 12, 3>
      <<<dim3(48, 12), 256, 0, stream>>>(B2, W3t, B1);
  // gated3 -> B2(80,12^3)
  k_gated<<<dim3(7, 80, 16), 256, 0, stream>>>(B1, B2, 1728, 96, 16, 16, 8, 3, 8, 5, 0, 1, 80);
  // conv4: B2(80,12^3) -> B1(64,16^3)  [S1 pad4]
  conv5<1, 80, 64, 8, 12, 16, 4, 4, 16, 4>
      <<<dim3(64, 8), 256, 0, stream>>>(B2, W4t, B1);
  // relu + spatial mean -> hb[16*64]
  k_relu_avg<<<1024, 256, 0, stream>>>(B1, hb);
  // linear -> out[16*10]
  k_linear<<<1, 256, 0, stream>>>(hb, Wl, bl, out);
}

// Round 4
// 5534.967 us; speedup vs baseline: 2.7054x; 1.2281x over previous
//
#include <hip/hip_runtime.h>
#include <math.h>

// SE3Net forward, fp32.
//   blurZ,blurY(x) -> conv1(5^3,p4,+fused x-blur) -> gated
//   -> blurZ,blurY(expand) -> conv2(5^3,s2,p2,+fused x-blur) -> gated
//   -> blurZ,blurY(expand) -> conv3(5^3,s2,p2,+fused x-blur, split-K) -> gated(sum)
//   -> conv4(5^3,p4) -> relu+avg -> linear
// Identity: conv(pad4,s1) is a FULL conv, so downsample(G*(W*x)) ==
// downsample(W*(G_exp*x)) with G_exp on its full support (D->D+4).
// Blur is separable: z,y as standalone passes, x fused into conv LDS staging.

struct GaussW { float g[5]; };
#define B_ 16

// ---------------- separable 1D blur pass along z (AXIS=2) or y (AXIS=1) ----
// in dims (DZ,DY,DX) per bc; EXP=1 expands the blurred axis by 4 (full
// support), EXP=0 keeps size (crop, offset 2). float4 along x.
template<int NBC, int DZ, int DY, int DX, int AXIS, int EXP>
__global__ __launch_bounds__(256) void blur1d(
    const float* __restrict__ in, float* __restrict__ out, GaussW gw)
{
  constexpr int DZO = DZ + ((AXIS == 2 && EXP) ? 4 : 0);
  constexpr int DYO = DY + ((AXIS == 1 && EXP) ? 4 : 0);
  constexpr int OFF = EXP ? 4 : 2;
  constexpr int NV  = DX / 4;
  constexpr int TOT = NBC * DZO * DYO * NV;
  int idx = blockIdx.x * 256 + threadIdx.x;
  if (idx >= TOT) return;
  int xv = idx % NV;
  int t  = idx / NV;
  int y  = t % DYO;
  t /= DYO;
  int z  = t % DZO;
  int bc = t / DZO;
  const float* p = in + (size_t)bc * DZ * DY * DX;
  float4 s = make_float4(0.f, 0.f, 0.f, 0.f);
  #pragma unroll
  for (int k = 0; k < 5; ++k) {
    int c = (AXIS == 2 ? z : y) + k - OFF;
    if (c < 0 || c >= (AXIS == 2 ? DZ : DY)) continue;
    const float4 v = *(const float4*)(p +
        (AXIS == 2 ? ((size_t)c * DY + y) : ((size_t)z * DY + c)) * DX + 4 * xv);
    float g = gw.g[k];
    s.x = fmaf(g, v.x, s.x);
    s.y = fmaf(g, v.y, s.y);
    s.z = fmaf(g, v.z, s.z);
    s.w = fmaf(g, v.w, s.w);
  }
  *(float4*)(out + (((size_t)bc * DZO + z) * DYO + y) * DX + 4 * xv) = s;
}

// ---------------- weight transpose: W[co][ci][125] -> Wt[ci][k][COP], pad 0 --
template<int CIN, int COUT, int COP>
__global__ __launch_bounds__(256) void k_transpose_w(
    const float* __restrict__ W, float* __restrict__ Wt)
{
  constexpr int TOT = CIN * 125 * COP;
  int idx = blockIdx.x * 256 + threadIdx.x;
  if (idx >= TOT) return;
  int co = idx % COP;
  int k  = (idx / COP) % 125;
  int ci = idx / (COP * 125);
  Wt[idx] = (co < COUT) ? W[((size_t)co * CIN + ci) * 125 + k] : 0.f;
}

// ---------------- tiled direct 5^3 conv ------------------------------------
// in: [B][CIN][DIN(z)][DIN(y)][XSRC(x)] (XSRC<DIN when FUSEX: x-blur fused
// into staging). wt: [CIN][125][COP]. out: [B][COUT][DOUT^3] (+split stride).
// Block: NCB co-groups (COB each) x SPTP spatial threads. Per thread: XB
// consecutive x outputs x COB channels. Weights read via wave-uniform
// (readfirstlane) addresses -> scalar loads. Input tile staged per ci in LDS
// (parity de-interleaved if S==2), window reads are b128/b64.
template<int S, int CIN, int CSPLIT, int COUT, int COP, int COB, int NCB,
         int DIN, int XSRC, int DOUT, int PAD, int ZT, int YT, int XB,
         int SPTP, int FUSEX, int XOFF, int CIB>
__global__ __launch_bounds__(256)
void convK(const float* __restrict__ in, const float* __restrict__ wt,
           float* __restrict__ out, size_t split_stride, GaussW gw)
{
  constexpr int K = 5;
  static_assert(DOUT % XB == 0, "XB must divide DOUT");
  constexpr int XQ  = DOUT / XB;
  constexpr int SPT = ZT * YT * XQ;
  static_assert(SPT <= SPTP, "SPTP too small");
  constexpr int NTH = SPTP * NCB;
  static_assert(NTH == 256, "block size 256");
  constexpr int XIN = (DOUT - 1) * S + K;
  constexpr int YIN = (YT - 1) * S + K;
  constexpr int ZIN = (ZT - 1) * S + K;
  constexpr int HXP = (S == 2) ? ((DOUT + 2 + 3) & ~3) : 0;
  constexpr int RW0 = (S == 2) ? (2 * HXP) : ((XIN + 3) & ~3);
  constexpr int RW  = (RW0 % 32 == 0 || RW0 % 32 == 16) ? (RW0 + 4) : RW0;
  constexpr int NROW = ZIN * YIN;
  constexpr int NIN  = NROW * RW;
  static_assert(DOUT % ZT == 0, "ZT must divide DOUT");
  constexpr int NZT = DOUT / ZT;
  constexpr int NYT = (DOUT + YT - 1) / YT;
  constexpr int D2  = DOUT * DOUT;
  constexpr int CI_PER = CIN / CSPLIT;
  static_assert(CI_PER % CIB == 0, "CIB must divide CI_PER");

  __shared__ __align__(16) float s_in[CIB][NIN];

  const int tid = threadIdx.x;
  const int cbg = __builtin_amdgcn_readfirstlane(tid / SPTP);  // wave-uniform
  const int sp  = tid % SPTP;

  const int bxi = blockIdx.x;
  const int yt  = bxi % NYT;
  const int zt  = (bxi / NYT) % NZT;
  const int b   = bxi / (NYT * NZT);
  const int cb  = blockIdx.y;
  const int spl = blockIdx.z;
  const int co0 = cb * (COB * NCB) + cbg * COB;
  const int oz0 = zt * ZT;
  const int oy0 = yt * YT;
  const int ci0 = spl * CI_PER;

  bool act = sp < SPT;
  int txq = act ? sp % XQ : 0;
  int t2  = act ? sp / XQ : 0;
  int tyl = t2 % YT;
  int tzl = t2 / YT;
  act = act && (oy0 + tyl < DOUT);
  if (!act) { txq = 0; tyl = 0; tzl = 0; }

  float acc[XB][COB];
  #pragma unroll
  for (int j = 0; j < XB; ++j)
    #pragma unroll
    for (int c = 0; c < COB; ++c) acc[j][c] = 0.f;

  for (int r = 0; r < CI_PER; r += CIB) {
    __syncthreads();
    // ---- stage CIB input channels (zero-padded; x-blur fused if FUSEX) ----
    for (int i = tid; i < CIB * NIN; i += NTH) {
      int cc = i / NIN;
      int w  = i - cc * NIN;
      int row = w / RW;
      int wx  = w - row * RW;
      int sz = row / YIN;
      int sy = row - sz * YIN;
      int u;
      if (S == 2) u = (wx < HXP) ? (2 * wx) : (wx < 2 * HXP ? 2 * (wx - HXP) + 1 : -1);
      else        u = (wx < XIN) ? wx : -1;
      int gz = oz0 * S + sz - PAD;
      int gy = oy0 * S + sy - PAD;
      int gx = u - PAD;
      float v = 0.f;
      if (u >= 0 && gz >= 0 && gz < DIN && gy >= 0 && gy < DIN &&
          gx >= 0 && gx < DIN) {
        const float* src = in +
            (((size_t)b * CIN + (ci0 + r + cc)) * DIN + gz) * ((size_t)DIN * XSRC) +
            (size_t)gy * XSRC;
        if constexpr (FUSEX) {
          float sacc = 0.f;
          #pragma unroll
          for (int tp = 0; tp < 5; ++tp) {
            int xs = gx + tp - XOFF;
            if (xs >= 0 && xs < XSRC) sacc = fmaf(gw.g[tp], src[xs], sacc);
          }
          v = sacc;
        } else {
          v = src[gx];
        }
      }
      s_in[cc][w] = v;
    }
    __syncthreads();
    // ---- accumulate ----
    #pragma unroll 1
    for (int cc = 0; cc < CIB; ++cc) {
      const int ci = ci0 + r + cc;
      const float* wci = wt + (size_t)ci * 125 * COP + co0;  // wave-uniform
      #pragma unroll 1
      for (int kz = 0; kz < K; ++kz) {
        #pragma unroll 1
        for (int ky = 0; ky < K; ++ky) {
          const float* rp = &s_in[cc][((tzl * S + kz) * YIN + (tyl * S + ky)) * RW];
          float fe[8], fo[8];
          if constexpr (S == 2) {
            const float* ep = rp + XB * txq;
            const float* op = rp + HXP + XB * txq;
            if constexpr ((XB & 3) == 0) {
              float4 a = *(const float4*)ep, b4 = *(const float4*)(ep + 4);
              fe[0]=a.x; fe[1]=a.y; fe[2]=a.z; fe[3]=a.w;
              fe[4]=b4.x; fe[5]=b4.y; fe[6]=b4.z; fe[7]=b4.w;
              float4 c4 = *(const float4*)op, d4 = *(const float4*)(op + 4);
              fo[0]=c4.x; fo[1]=c4.y; fo[2]=c4.z; fo[3]=c4.w;
              fo[4]=d4.x; fo[5]=d4.y; fo[6]=d4.z; fo[7]=d4.w;
            } else {
              #pragma unroll
              for (int q = 0; q < 4; ++q) {
                float2 a = *(const float2*)(ep + 2 * q);
                fe[2*q] = a.x; fe[2*q+1] = a.y;
                float2 b2 = *(const float2*)(op + 2 * q);
                fo[2*q] = b2.x; fo[2*q+1] = b2.y;
              }
            }
          } else {
            const float* wp0 = rp + XB * txq;
            float4 a = *(const float4*)wp0, b4 = *(const float4*)(wp0 + 4);
            fe[0]=a.x; fe[1]=a.y; fe[2]=a.z; fe[3]=a.w;
            fe[4]=b4.x; fe[5]=b4.y; fe[6]=b4.z; fe[7]=b4.w;
            fo[0]=0.f; fo[1]=0.f; fo[2]=0.f; fo[3]=0.f;
            fo[4]=0.f; fo[5]=0.f; fo[6]=0.f; fo[7]=0.f;
          }
          const float* wk = wci + (kz * 25 + ky * 5) * COP;
          #pragma unroll
          for (int kx = 0; kx < K; ++kx) {
            const float* wp = wk + kx * COP;
            float wv[COB];
            #pragma unroll
            for (int c = 0; c < COB; ++c) wv[c] = wp[c];  // scalar loads
            #pragma unroll
            for (int j = 0; j < XB; ++j) {
              float iv;
              if constexpr (S == 2)
                iv = (kx & 1) ? fo[j + (kx >> 1)] : fe[j + (kx >> 1)];
              else
                iv = fe[j + kx];
              #pragma unroll
              for (int c = 0; c < COB; ++c)
                acc[j][c] = fmaf(iv, wv[c], acc[j][c]);
            }
          }
        }
      }
    }
  }
  // ---- store ----
  if (act) {
    const int oz = oz0 + tzl, oy = oy0 + tyl, ox = txq * XB;
    float* ob = out + (size_t)spl * split_stride;
    #pragma unroll
    for (int c = 0; c < COB; ++c) {
      int co = co0 + c;
      if (co < COUT) {
        float* p = ob + (((size_t)b * COUT + co) * DOUT + oz) * D2 +
                   (size_t)oy * DOUT + ox;
        if constexpr ((XB & 3) == 0) {
          #pragma unroll
          for (int q = 0; q < XB / 4; ++q)
            *(float4*)(p + 4 * q) = make_float4(acc[4*q][c], acc[4*q+1][c],
                                                acc[4*q+2][c], acc[4*q+3][c]);
        } else {
          #pragma unroll
          for (int q = 0; q < XB / 2; ++q)
            *(float2*)(p + 2 * q) = make_float2(acc[2*q][c], acc[2*q+1][c]);
        }
      }
    }
  }
}

// ---------------- gated nonlinearity (float4, optional split-K sum) --------
__global__ __launch_bounds__(256) void k_gated4(
    const float* __restrict__ in, const float* __restrict__ in2,
    float* __restrict__ out, int S3v, int Cin, int n_scalar, int n_gate,
    int m1, int d1, int m2, int d2, int m3, int d3, int n_out)
{
  int idx = blockIdx.x * 256 + threadIdx.x;
  int oc = blockIdx.y;
  int b  = blockIdx.z;
  if (idx >= S3v) return;
  size_t S3 = (size_t)S3v * 4;
  auto ld = [&](int ch) {
    size_t o = ((size_t)b * Cin + ch) * S3 + 4 * (size_t)idx;
    float4 v = *(const float4*)(in + o);
    if (in2) {
      float4 w = *(const float4*)(in2 + o);
      v.x += w.x; v.y += w.y; v.z += w.z; v.w += w.w;
    }
    return v;
  };
  float4 val;
  if (oc < n_scalar) {
    float4 v = ld(oc);
    val = make_float4(fmaxf(v.x, 0.f), fmaxf(v.y, 0.f),
                      fmaxf(v.z, 0.f), fmaxf(v.w, 0.f));
  } else {
    int o = oc - n_scalar;
    int gate_ch;
    if (o < m1 * d1) gate_ch = n_scalar + o / d1;
    else if (o - m1 * d1 < m2 * d2) gate_ch = n_scalar + m1 + (o - m1 * d1) / d2;
    else gate_ch = n_scalar + m1 + m2 + (o - m1 * d1 - m2 * d2) / d3;
    float4 v = ld(n_scalar + n_gate + o);
    float4 g = ld(gate_ch);
    val = make_float4(v.x / (1.f + expf(-g.x)), v.y / (1.f + expf(-g.y)),
                      v.z / (1.f + expf(-g.z)), v.w / (1.f + expf(-g.w)));
  }
  *(float4*)(out + ((size_t)b * n_out + oc) * S3 + 4 * (size_t)idx) = val;
}

// ---------------- relu + spatial mean --------------------------------------
__global__ __launch_bounds__(256) void k_relu_avg(
    const float* __restrict__ in, float* __restrict__ h)
{
  int bc = blockIdx.x;               // b*64 + c
  const float* p = in + (size_t)bc * 4096;
  float s = 0.f;
  for (int i = threadIdx.x; i < 1024; i += 256) {
    float4 v = *(const float4*)(p + 4 * i);
    s += fmaxf(v.x, 0.f) + fmaxf(v.y, 0.f) + fmaxf(v.z, 0.f) + fmaxf(v.w, 0.f);
  }
  #pragma unroll
  for (int off = 32; off > 0; off >>= 1) s += __shfl_down(s, off, 64);
  __shared__ float wsum[4];
  int wid = threadIdx.x >> 6;
  if ((threadIdx.x & 63) == 0) wsum[wid] = s;
  __syncthreads();
  if (threadIdx.x == 0)
    h[bc] = (wsum[0] + wsum[1] + wsum[2] + wsum[3]) * (1.f / 4096.f);
}

// ---------------- final linear [16,64] @ [10,64]^T + b ---------------------
__global__ __launch_bounds__(256) void k_linear(
    const float* __restrict__ h, const float* __restrict__ Wl,
    const float* __restrict__ bl, float* __restrict__ out)
{
  int t = threadIdx.x;
  if (t >= 160) return;
  int b = t / 10, o = t - b * 10;
  const float* hp = h + b * 64;
  const float* wp = Wl + o * 64;
  float s = bl[o];
  #pragma unroll
  for (int c = 0; c < 64; ++c) s = fmaf(hp[c], wp[c], s);
  out[t] = s;
}

extern "C" void kernel_launch(void* const* d_in, const int* in_sizes, int n_in,
                              void* d_out, int out_size, void* d_ws, size_t ws_size,
                              hipStream_t stream)
{
  const float* x  = (const float*)d_in[0];
  const float* W1 = (const float*)d_in[1];
  const float* W2 = (const float*)d_in[2];
  const float* W3 = (const float*)d_in[3];
  const float* W4 = (const float*)d_in[4];
  const float* Wl = (const float*)d_in[5];
  const float* bl = (const float*)d_in[6];
  float* out = (float*)d_out;
  float* ws  = (float*)d_ws;

  // gaussian taps (scale=2): sigma=0.5*sqrt(3), size 5, normalized
  GaussW gw;
  {
    double gv[5], sum = 0.0;
    for (int i = 0; i < 5; ++i) { double r = i - 2; gv[i] = exp(-r * r / 1.5); sum += gv[i]; }
    for (int i = 0; i < 5; ++i) gw.g[i] = (float)(gv[i] / sum);
  }

  // workspace (floats), 64-aligned chunks. Two big ping-pong regions A,B.
  size_t off = 0;
  auto A = [&](size_t n) { size_t o = off; off += (n + 63) & ~(size_t)63; return o; };
  size_t o_lp  = A(524288);              // z,y-blurred input 16x1x32^3
  size_t o_W1t = A(4000);                // [1][125][32]
  size_t o_W2t = A(300000);              // [25][125][96]
  size_t o_W3t = A(864000);              // [72][125][96]
  size_t o_W4t = A(640000);              // [80][125][64]
  size_t o_h   = A(1024);
  size_t o_A   = A(23040000);            // max: blur2-y out 16x25x(40,40,36)
  size_t o_B   = A(22394880);            // max: conv1 out 16x30x36^3
  if (ws_size < off * sizeof(float)) return;

  float* lp  = ws + o_lp;
  float* W1t = ws + o_W1t;
  float* W2t = ws + o_W2t;
  float* W3t = ws + o_W3t;
  float* W4t = ws + o_W4t;
  float* hb  = ws + o_h;
  float* Ab  = ws + o_A;
  float* Bb  = ws + o_B;

  // weight prep
  k_transpose_w<1, 30, 32><<<16, 256, 0, stream>>>(W1, W1t);
  k_transpose_w<25, 88, 96><<<(300000 + 255) / 256, 256, 0, stream>>>(W2, W2t);
  k_transpose_w<72, 96, 96><<<(864000 + 255) / 256, 256, 0, stream>>>(W3, W3t);
  k_transpose_w<80, 64, 64><<<(640000 + 255) / 256, 256, 0, stream>>>(W4, W4t);

  // input blur (crop): z pass x->A, y pass A->lp; x pass fused into conv1
  blur1d<16, 32, 32, 32, 2, 0><<<(16 * 32 * 32 * 8 + 255) / 256, 256, 0, stream>>>(x, Ab, gw);
  blur1d<16, 32, 32, 32, 1, 0><<<(16 * 32 * 32 * 8 + 255) / 256, 256, 0, stream>>>(Ab, lp, gw);

  // conv1: lp(1, 32^3 virtual, fused x crop-blur) -> B (30, 36^3)
  convK<1, 1, 1, 30, 32, 8, 2, 32, 32, 36, 4, 2, 7, 4, 128, 1, 2, 1>
      <<<dim3(16 * 18 * 6, 2, 1), 256, 0, stream>>>(lp, W1t, Bb, 0, gw);
  // gated1 -> A (25, 36^3)
  k_gated4<<<dim3(46, 25, 16), 256, 0, stream>>>(Bb, nullptr, Ab, 11664, 30, 2, 5,
                                                 2, 3, 2, 5, 1, 7, 25);
  // blur2 (expand): z A->B (40,36,36), y B->A (40,40,36)
  blur1d<400, 36, 36, 36, 2, 1><<<(400 * 40 * 36 * 9 + 255) / 256, 256, 0, stream>>>(Ab, Bb, gw);
  blur1d<400, 40, 36, 36, 1, 1><<<(400 * 40 * 40 * 9 + 255) / 256, 256, 0, stream>>>(Bb, Ab, gw);
  // conv2: A(25, 40^3 virtual, x from 36) -> B (88, 20^3)
  convK<2, 25, 1, 88, 96, 8, 2, 40, 36, 20, 2, 4, 6, 4, 128, 1, 4, 1>
      <<<dim3(16 * 5 * 4, 6, 1), 256, 0, stream>>>(Ab, W2t, Bb, 0, gw);
  // gated2 -> A (72, 20^3)
  k_gated4<<<dim3(8, 72, 16), 256, 0, stream>>>(Bb, nullptr, Ab, 2000, 88, 8, 16,
                                                8, 3, 8, 5, 0, 1, 72);
  // blur3 (expand): z A->B (24,20,20), y B->A (24,24,20)
  blur1d<1152, 20, 20, 20, 2, 1><<<(1152 * 24 * 20 * 5 + 255) / 256, 256, 0, stream>>>(Ab, Bb, gw);
  blur1d<1152, 24, 20, 20, 1, 1><<<(1152 * 24 * 24 * 5 + 255) / 256, 256, 0, stream>>>(Bb, Ab, gw);
  // conv3: A(72, 24^3 virtual, x from 20) -> B: P0, P1 (each 96, 12^3), split-K
  convK<2, 72, 2, 96, 96, 8, 4, 24, 20, 12, 2, 4, 8, 6, 64, 1, 4, 1>
      <<<dim3(16 * 3 * 2, 3, 2), 256, 0, stream>>>(Ab, W3t, Bb, 2654208, gw);
  // gated3 (sum splits) -> A (80, 12^3)
  k_gated4<<<dim3(2, 80, 16), 256, 0, stream>>>(Bb, Bb + 2654208, Ab, 432, 96, 16, 16,
                                                8, 3, 8, 5, 0, 1, 80);
  // conv4: A(80, 12^3) -> B (64, 16^3)   [DIN=XSRC=12 — was wrongly 16]
  convK<1, 80, 1, 64, 64, 8, 2, 12, 12, 16, 4, 2, 16, 4, 128, 0, 0, 2>
      <<<dim3(16 * 8, 4, 1), 256, 0, stream>>>(Ab, W4t, Bb, 0, gw);
  // relu + spatial mean -> hb[16*64]
  k_relu_avg<<<1024, 256, 0, stream>>>(Bb, hb);
  // linear -> out[16*10]
  k_linear<<<1, 256, 0, stream>>>(hb, Wl, bl, out);
}